// Round 11
// baseline (267.296 us; speedup 1.0000x reference)
//
#include <hip/hip_runtime.h>
#include <stdint.h>

typedef float  f32x4  __attribute__((ext_vector_type(4)));
typedef __bf16 bf16x8 __attribute__((ext_vector_type(8)));
typedef short  s16x8  __attribute__((ext_vector_type(8)));
typedef short  s16x4  __attribute__((ext_vector_type(4)));
typedef unsigned int   u32;
typedef unsigned short u16;
typedef u32 u32x2 __attribute__((ext_vector_type(2)));
typedef u32 u32x4 __attribute__((ext_vector_type(4)));

#define DM 1024
#define LQ 2048
#define NH 16

__device__ __forceinline__ u16 f2bf(float f) {
    unsigned int u = __builtin_bit_cast(unsigned int, f);
    u += 0x7FFFu + ((u >> 16) & 1u);
    return (u16)(u >> 16);
}

__device__ __forceinline__ float fexp2(float x) {
#if __has_builtin(__builtin_amdgcn_exp2f)
    return __builtin_amdgcn_exp2f(x);
#else
    return exp2f(x);
#endif
}

__device__ __forceinline__ u32 cvtpk(float lo, float hi) {
    u32 r;
    asm("v_cvt_pk_bf16_f32 %0, %1, %2" : "=v"(r) : "v"(lo), "v"(hi));
    return r;
}

__device__ __forceinline__ float max3f(float a, float b, float c) {
    float r;
    asm("v_max3_f32 %0, %1, %2, %3" : "=v"(r) : "v"(a), "v"(b), "v"(c));
    return r;
}

__device__ __forceinline__ u32 permb(u32 b, u32 a, u32 sel) {
    u32 r;
    asm("v_perm_b32 %0, %1, %2, %3" : "=v"(r) : "v"(b), "v"(a), "s"(sel));
    return r;
}

__device__ __forceinline__ f32x4 mfma32(s16x8 a, s16x8 b, f32x4 c) {
    return __builtin_amdgcn_mfma_f32_16x16x32_bf16(
        __builtin_bit_cast(bf16x8, a), __builtin_bit_cast(bf16x8, b), c, 0, 0, 0);
}

#define GLD16(gp, lp) __builtin_amdgcn_global_load_lds( \
    (__attribute__((address_space(1))) void*)(gp),      \
    (__attribute__((address_space(3))) void*)(lp), 16, 0, 0)

__global__ void k_mask_check(const int4* __restrict__ m4, int n4, int* flag) {
    bool z = false;
    for (int i = blockIdx.x * blockDim.x + threadIdx.x; i < n4;
         i += gridDim.x * blockDim.x) {
        int4 v = m4[i];
        if (v.x == 0 || v.y == 0 || v.z == 0 || v.w == 0) z = true;
    }
    if (__ballot(z)) {
        if ((threadIdx.x & 63) == 0) atomicAnd(flag, 0);
    }
}

// One fused fp32->bf16 convert pass over q,k,v,wq,wk,wv,wo. Also inits flag.
__global__ void k_cvt_all(const float4* __restrict__ q,  const float4* __restrict__ k,
                          const float4* __restrict__ v,  const float4* __restrict__ wq,
                          const float4* __restrict__ wk, const float4* __restrict__ wv,
                          const float4* __restrict__ wo,
                          uint64_t* xq, uint64_t* xk, uint64_t* xv,
                          uint64_t* bwq, uint64_t* bwk, uint64_t* bwv, uint64_t* bwo,
                          int* flag)
{
    if (blockIdx.x == 0 && threadIdx.x == 0) *flag = 1;
    const int NX = 2097152, NW = 262144;   // 2^21, 2^18 float4-chunks
    const int total = 3 * NX + 4 * NW;
    const int stride = gridDim.x * blockDim.x;
    for (int idx = blockIdx.x * blockDim.x + threadIdx.x; idx < total; idx += stride) {
        const float4* s; uint64_t* d; int off;
        if (idx < 3 * NX) {
            int ji = idx >> 21;
            off = idx & (NX - 1);
            s = ji == 0 ? q : ji == 1 ? k : v;
            d = ji == 0 ? xq : ji == 1 ? xk : xv;
        } else {
            int r = idx - 3 * NX;
            int ji = r >> 18;
            off = r & (NW - 1);
            s = ji == 0 ? wq : ji == 1 ? wk : ji == 2 ? wv : wo;
            d = ji == 0 ? bwq : ji == 1 ? bwk : ji == 2 ? bwv : bwo;
        }
        float4 f = s[off];
        union { u16 u[4]; uint64_t qq; } rr;
        rr.u[0] = f2bf(f.x); rr.u[1] = f2bf(f.y);
        rr.u[2] = f2bf(f.z); rr.u[3] = f2bf(f.w);
        d[off] = rr.qq;
    }
}

// C = A(MxK) * B(NxK)^T, swapped-operand MFMA: D[n][m], vectorized stores.
// XCD swizzle: each XCD owns 8 contiguous m-panels x all n (A+B L2-resident).
// MODE 0: fused QKV via blockIdx.z; bf16 store to head-split [B*H][L][64].
// MODE 1: fp32 store, plain row-major [M][N] (output projection).
template <int MODE>
__global__ __launch_bounds__(256) void k_gemm(
    const u16* __restrict__ A0, const u16* __restrict__ Bw0,
    u16* __restrict__ Cb0, float* __restrict__ Cf, float scale)
{
    constexpr int K = 1024;
    __shared__ char lA[128 * 32 * 2];
    __shared__ char lB[128 * 32 * 2];
    const int t = threadIdx.x, l = t & 63, w = t >> 6;
    const int q = l & 15, g = l >> 4;
    const int z = (MODE == 0) ? blockIdx.z : 0;
    const u16* A  = A0  + (size_t)z * 8388608;
    const u16* Bw = Bw0 + (size_t)z * 1048576;
    u16* Cb = (MODE == 0) ? Cb0 + (size_t)z * 8388608 : nullptr;
    const float scl = (MODE == 0 && z != 0) ? 1.0f : scale;
    const int lin = blockIdx.x;                       // 0..511
    const int ytile = ((lin & 7) << 3) | ((lin >> 3) & 7);
    const int xtile = lin >> 6;
    const int m0 = ytile * 128, n0 = xtile * 128;
    const int wr = (w >> 1) * 64, wc = (w & 1) * 64;

    f32x4 acc[4][4];
#pragma unroll
    for (int i = 0; i < 4; i++)
#pragma unroll
        for (int j = 0; j < 4; j++) acc[i][j] = (f32x4){0.f, 0.f, 0.f, 0.f};

    for (int k0 = 0; k0 < K; k0 += 32) {
#pragma unroll
        for (int c = 0; c < 2; c++) {
            int i = c * 256 + t;
            int row = i >> 2, sl = i & 3;
            int ss = sl ^ (row & 3);
            GLD16(A  + (size_t)(m0 + row) * K + k0 + ss * 8, lA + (i - l) * 16);
            GLD16(Bw + (size_t)(n0 + row) * K + k0 + ss * 8, lB + (i - l) * 16);
        }
        __syncthreads();
        s16x8 af[4], bfr[4];
#pragma unroll
        for (int mt = 0; mt < 4; mt++) {
            int r = wr + mt * 16 + q;
            af[mt] = *(const s16x8*)(lA + r * 64 + ((g ^ (r & 3)) * 16));
        }
#pragma unroll
        for (int nt = 0; nt < 4; nt++) {
            int r = wc + nt * 16 + q;
            bfr[nt] = *(const s16x8*)(lB + r * 64 + ((g ^ (r & 3)) * 16));
        }
#pragma unroll
        for (int mt = 0; mt < 4; mt++)
#pragma unroll
            for (int nt = 0; nt < 4; nt++)
                acc[mt][nt] = mfma32(bfr[nt], af[mt], acc[mt][nt]);
        __syncthreads();
    }

#pragma unroll
    for (int mt = 0; mt < 4; mt++) {
        int m = m0 + wr + mt * 16 + q;   // token (lane-contiguous)
#pragma unroll
        for (int nt = 0; nt < 4; nt++) {
            int n = n0 + wc + nt * 16 + g * 4;   // 4-consecutive n run
            f32x4 a = acc[mt][nt];
            if (MODE == 0) {
                int bb = m >> 11, row = m & 2047;
                int h = n >> 6, d = n & 63;
                s16x4 pk;
#pragma unroll
                for (int j = 0; j < 4; j++) pk[j] = (short)f2bf(a[j] * scl);
                *(s16x4*)(Cb + (((size_t)(bb * NH + h) * LQ + row) << 6) + d) = pk;
            } else {
                f32x4 o;
#pragma unroll
                for (int j = 0; j < 4; j++) o[j] = a[j] * scl;
                *(f32x4*)(Cf + (size_t)m * DM + n) = o;
            }
        }
    }
}

// Flash attention, swapped-QK^T in-register softmax, mfma32 PV (permuted-kc).
// This round: (a) V-staging thread remap (dg/kg) so ds_write_b64 hits the
// 4-lane/slot floor (was 8-way conflicted); (b) 128 q-rows/block, grid 1024,
// 4 blocks/CU for latency hiding (occupancy 19% -> ~38%).
__global__ __launch_bounds__(256, 4) void k_attn(
    const u16* __restrict__ Qh, const u16* __restrict__ Kh,
    const u16* __restrict__ Vh, u16* __restrict__ ctx,
    const int* __restrict__ mask, const int* __restrict__ flag)
{
    __shared__ char lds[32768];
    char* lK0 = lds;           // lK[b] = lds + b*8192       [kc][d] 16B-xor-swz
    char* lV0 = lds + 16384;   // lV[b]: [d][kc-permuted], 16B-unit swz u^(d&7)
    const int t = threadIdx.x, l = t & 63, w = t >> 6;
    const int g = l >> 4, q = l & 15;
    const int p = blockIdx.x;
    const int bh = (p & 7) * 8 + ((p >> 3) >> 4);   // XCD-contiguous heads
    const int qt = ((p >> 3) & 15) * 128;
    const int allones = *flag;
    const size_t base = (size_t)bh * LQ * 64;
    // V-staging thread remap: per-wave kg spans both bb2 parities and 4 kg&3
    // values -> 16 write slots x 4 lanes = conflict floor.
    const int dg = (l & 7) | ((w >> 1) << 3);
    const int kg = (l >> 3) | ((w & 1) << 3);

    s16x8 qf[2][2];   // Q pre-scaled by log2(e)/8
#pragma unroll
    for (int qh = 0; qh < 2; qh++)
#pragma unroll
        for (int kh = 0; kh < 2; kh++)
            qf[qh][kh] = *(const s16x8*)(
                Qh + base + (size_t)(qt + w * 32 + qh * 16 + q) * 64 + kh * 32 + g * 8);

    f32x4 oacc[2][4];
#pragma unroll
    for (int qh = 0; qh < 2; qh++)
#pragma unroll
        for (int dt = 0; dt < 4; dt++) oacc[qh][dt] = (f32x4){0.f, 0.f, 0.f, 0.f};
    float mrow[2] = {-1e30f, -1e30f}, lrow[2] = {0.f, 0.f};

    auto stageK = [&](int kt, int b) {
#pragma unroll
        for (int c = 0; c < 2; c++) {
            int i = c * 256 + t;
            int row = i >> 3, sl = i & 7;
            GLD16(Kh + base + (size_t)(kt + row) * 64 + ((sl ^ (row & 7)) * 8),
                  lK0 + b * 8192 + (i - l) * 16);
        }
    };
    auto loadV = [&](int kt, s16x4* vr) {
#pragma unroll
        for (int j = 0; j < 4; j++)
            vr[j] = *(const s16x4*)(Vh + base + (size_t)(kt + kg * 4 + j) * 64 + dg * 4);
    };
    auto writeV = [&](const s16x4* vr, int b) {
        const u32 selLO = 0x05040100u, selHI = 0x07060302u;
        const int u = ((kg & 8) >> 1) | (kg & 3);
        const int bb2 = (kg >> 2) & 1;
        u32x2 vv[4];
#pragma unroll
        for (int j = 0; j < 4; j++) vv[j] = __builtin_bit_cast(u32x2, vr[j]);
#pragma unroll
        for (int jj = 0; jj < 4; jj++) {
            int d = dg * 4 + jj;
            u32 a0 = vv[0][jj >> 1], a1 = vv[1][jj >> 1];
            u32 a2 = vv[2][jj >> 1], a3 = vv[3][jj >> 1];
            u32 sel = (jj & 1) ? selHI : selLO;
            u32x2 pw = {permb(a1, a0, sel), permb(a3, a2, sel)};
            *(s16x4*)(lV0 + b * 8192 + d * 128 + ((u ^ (d & 7)) * 16) + bb2 * 8) =
                __builtin_bit_cast(s16x4, pw);
        }
    };

    { // prologue: tile 0 into buffer 0
        s16x4 vr[4];
        stageK(0, 0);
        loadV(0, vr);
        writeV(vr, 0);
    }

    int cur = 0;
    for (int kt = 0; kt < LQ; kt += 64) {
        __syncthreads();   // tile `cur` staged (vmcnt/lgkm drained), prev consumed
        const bool more = (kt + 64) < LQ;
        s16x4 vr[4];
        if (more) {        // issue next-tile staging early; latency hides under compute
            stageK(kt + 64, cur ^ 1);
            loadV(kt + 64, vr);
        }

        // --- S^T = K Q^T : lane holds row q=l&15, kc = ct*16 + g*4 + r
        f32x4 sc[2][4];
#pragma unroll
        for (int qh = 0; qh < 2; qh++)
#pragma unroll
            for (int ct = 0; ct < 4; ct++) sc[qh][ct] = (f32x4){0.f, 0.f, 0.f, 0.f};
        __builtin_amdgcn_s_setprio(1);
#pragma unroll
        for (int ct = 0; ct < 4; ct++) {
            int kc = ct * 16 + q;
#pragma unroll
            for (int kh = 0; kh < 2; kh++) {
                s16x8 kf = *(const s16x8*)(lK0 + cur * 8192 + kc * 128 +
                                           (((kh * 4 + g) ^ (kc & 7)) * 16));
#pragma unroll
                for (int qh = 0; qh < 2; qh++)
                    sc[qh][ct] = mfma32(kf, qf[qh][kh], sc[qh][ct]);
            }
        }
        __builtin_amdgcn_s_setprio(0);

        if (!allones) {   // slow correct path (unused for all-ones mask)
            int b = bh >> 4;
#pragma unroll
            for (int qh = 0; qh < 2; qh++)
#pragma unroll
                for (int ct = 0; ct < 4; ct++)
#pragma unroll
                    for (int r = 0; r < 4; r++) {
                        int qr = qt + w * 32 + qh * 16 + q;
                        int kc = kt + ct * 16 + g * 4 + r;
                        if (mask[(size_t)(b * LQ + qr) * LQ + kc] == 0)
                            sc[qh][ct][r] = -1e9f;
                    }
        }

        // --- online softmax (log2 domain); row max via v_max3 tree + 2 shfl
        float pm[2];
#pragma unroll
        for (int qh = 0; qh < 2; qh++) {
            float m0 = max3f(sc[qh][0][0], sc[qh][0][1], sc[qh][0][2]);
            m0 = max3f(m0, sc[qh][0][3], sc[qh][1][0]);
            m0 = max3f(m0, sc[qh][1][1], sc[qh][1][2]);
            m0 = max3f(m0, sc[qh][1][3], sc[qh][2][0]);
            m0 = max3f(m0, sc[qh][2][1], sc[qh][2][2]);
            m0 = max3f(m0, sc[qh][2][3], sc[qh][3][0]);
            m0 = max3f(m0, sc[qh][3][1], sc[qh][3][2]);
            m0 = fmaxf(m0, sc[qh][3][3]);
            m0 = fmaxf(m0, __shfl_xor(m0, 16, 64));
            m0 = fmaxf(m0, __shfl_xor(m0, 32, 64));
            pm[qh] = m0;
        }
        bool ok = (pm[0] <= mrow[0] + 8.f) && (pm[1] <= mrow[1] + 8.f);
        if (!__all(ok)) {
#pragma unroll
            for (int qh = 0; qh < 2; qh++) {
                float nm = fmaxf(mrow[qh], pm[qh]);
                float corr = fexp2(mrow[qh] - nm);
                mrow[qh] = nm;
                lrow[qh] *= corr;
                float cv[4];
#pragma unroll
                for (int r = 0; r < 4; r++) cv[r] = __shfl(corr, g * 4 + r, 64);
#pragma unroll
                for (int dt = 0; dt < 4; dt++)
#pragma unroll
                    for (int r = 0; r < 4; r++) oacc[qh][dt][r] *= cv[r];
            }
        }
        // exp + rowsum + pack A-fragments for mfma32 PV (permuted-kc, lane-local)
        s16x8 pa32[2][2];
#pragma unroll
        for (int qh = 0; qh < 2; qh++) {
            float rs = 0.f;
#pragma unroll
            for (int ct = 0; ct < 4; ct++)
#pragma unroll
                for (int r = 0; r < 4; r++) {
                    float e = fexp2(sc[qh][ct][r] - mrow[qh]);
                    sc[qh][ct][r] = e;
                    rs += e;
                }
            rs += __shfl_xor(rs, 16, 64);
            rs += __shfl_xor(rs, 32, 64);
            lrow[qh] += rs;
#pragma unroll
            for (int s = 0; s < 2; s++) {
                u32x4 pv;
                pv.x = cvtpk(sc[qh][2 * s][0],     sc[qh][2 * s][1]);
                pv.y = cvtpk(sc[qh][2 * s][2],     sc[qh][2 * s][3]);
                pv.z = cvtpk(sc[qh][2 * s + 1][0], sc[qh][2 * s + 1][1]);
                pv.w = cvtpk(sc[qh][2 * s + 1][2], sc[qh][2 * s + 1][3]);
                pa32[qh][s] = __builtin_bit_cast(s16x8, pv);
            }
        }

        // --- O += P V  (mfma32, B-fragment = one ds_read_b128 per (dt,s))
        __builtin_amdgcn_s_setprio(1);
#pragma unroll
        for (int dt = 0; dt < 4; dt++) {
#pragma unroll
            for (int s = 0; s < 2; s++) {
                s16x8 vf = *(const s16x8*)(lV0 + cur * 8192 + (dt * 16 + q) * 128 +
                                           (((4 * s + g) ^ (q & 7)) * 16));
#pragma unroll
                for (int qh = 0; qh < 2; qh++)
                    oacc[qh][dt] = mfma32(pa32[qh][s], vf, oacc[qh][dt]);
            }
        }
        __builtin_amdgcn_s_setprio(0);

        if (more) writeV(vr, cur ^ 1);   // vmcnt wait lands here, after compute
        cur ^= 1;
    }

    // --- epilogue: normalize -> per-wave LDS region (swizzled) -> 64B/lane stores
    __syncthreads();                  // all waves done reading lK/lV
    char* eb = lds + w * 4096;        // 32 rows x 128B per wave
#pragma unroll
    for (int qh = 0; qh < 2; qh++) {
        float lv[4];
#pragma unroll
        for (int r = 0; r < 4; r++) lv[r] = 1.f / __shfl(lrow[qh], g * 4 + r, 64);
#pragma unroll
        for (int dt = 0; dt < 4; dt++)
#pragma unroll
            for (int r = 0; r < 4; r++) {
                int row = qh * 16 + g * 4 + r;
                int cb = ((dt * 16 + q) * 2) ^ ((row & 7) << 4);
                *(u16*)(eb + row * 128 + cb) = f2bf(oacc[qh][dt][r] * lv[r]);
            }
    }
    __syncthreads();
    const int b = bh >> 4, h = bh & 15;
    const int er = l >> 1, eh = l & 1;
    const int token = qt + w * 32 + er;
    u16* gp = ctx + (size_t)(b * LQ + token) * DM + h * 64 + eh * 32;
#pragma unroll
    for (int j = 0; j < 4; j++) {
        int cb = (eh * 64 + j * 16) ^ ((er & 7) << 4);
        *(s16x8*)(gp + j * 8) = *(const s16x8*)(eb + er * 128 + cb);
    }
}

extern "C" void kernel_launch(void* const* d_in, const int* in_sizes, int n_in,
                              void* d_out, int out_size, void* d_ws, size_t ws_size,
                              hipStream_t stream)
{
    const float* q  = (const float*)d_in[0];
    const float* k  = (const float*)d_in[1];
    const float* v  = (const float*)d_in[2];
    const float* wq = (const float*)d_in[3];
    const float* wk = (const float*)d_in[4];
    const float* wv = (const float*)d_in[5];
    const float* wo = (const float*)d_in[6];
    const int* mask = (const int*)d_in[7];

    char* ws = (char*)d_ws;
    const size_t SX = (size_t)8192 * 1024 * 2;
    const size_t SW = (size_t)1024 * 1024 * 2;
    u16* xq  = (u16*)(ws);                     // xq,xk,xv contiguous (8M u16 each)
    u16* xk  = (u16*)(ws + SX);
    u16* xv  = (u16*)(ws + 2 * SX);
    u16* bwq = (u16*)(ws + 3 * SX);            // bwq,bwk,bwv contiguous (1M u16 each)
    u16* bwk = (u16*)(ws + 3 * SX + SW);
    u16* bwv = (u16*)(ws + 3 * SX + 2 * SW);
    u16* bwo = (u16*)(ws + 3 * SX + 3 * SW);
    u16* Qh  = (u16*)(ws + 3 * SX + 4 * SW);   // Qh,Kh,Vh contiguous (8M u16 each)
    u16* Kh  = (u16*)(ws + 4 * SX + 4 * SW);
    u16* Vh  = (u16*)(ws + 5 * SX + 4 * SW);
    u16* ctx = (u16*)(ws + 6 * SX + 4 * SW);
    int* flag = (int*)(ws + 7 * SX + 4 * SW);

    k_cvt_all<<<2048, 256, 0, stream>>>(
        (const float4*)q, (const float4*)k, (const float4*)v,
        (const float4*)wq, (const float4*)wk, (const float4*)wv, (const float4*)wo,
        (uint64_t*)xq, (uint64_t*)xk, (uint64_t*)xv,
        (uint64_t*)bwq, (uint64_t*)bwk, (uint64_t*)bwv, (uint64_t*)bwo, flag);
    k_mask_check<<<2048, 256, 0, stream>>>((const int4*)mask,
                                           (4 * 2048 * 2048) / 4, flag);

    // Fused QKV projection (z selects q/k/v); Q scaled by log2(e)/8 (exp2 softmax)
    k_gemm<0><<<dim3(512, 1, 3), 256, 0, stream>>>(xq, bwq, Qh, nullptr,
                                                   0.18033688011112042f);

    k_attn<<<1024, 256, 0, stream>>>(Qh, Kh, Vh, ctx, mask, flag);

    k_gemm<1><<<dim3(512), 256, 0, stream>>>(ctx, bwo, nullptr, (float*)d_out, 1.0f);
}

// Round 12
// 236.672 us; speedup vs baseline: 1.1294x; 1.1294x over previous
//
#include <hip/hip_runtime.h>
#include <stdint.h>

typedef float  f32x4  __attribute__((ext_vector_type(4)));
typedef __bf16 bf16x8 __attribute__((ext_vector_type(8)));
typedef short  s16x8  __attribute__((ext_vector_type(8)));
typedef short  s16x4  __attribute__((ext_vector_type(4)));
typedef unsigned int   u32;
typedef unsigned short u16;
typedef u32 u32x2 __attribute__((ext_vector_type(2)));
typedef u32 u32x4 __attribute__((ext_vector_type(4)));

#define DM 1024
#define LQ 2048
#define NH 16

__device__ __forceinline__ u16 f2bf(float f) {
    unsigned int u = __builtin_bit_cast(unsigned int, f);
    u += 0x7FFFu + ((u >> 16) & 1u);
    return (u16)(u >> 16);
}

__device__ __forceinline__ float fexp2(float x) {
#if __has_builtin(__builtin_amdgcn_exp2f)
    return __builtin_amdgcn_exp2f(x);
#else
    return exp2f(x);
#endif
}

__device__ __forceinline__ u32 cvtpk(float lo, float hi) {
    u32 r;
    asm("v_cvt_pk_bf16_f32 %0, %1, %2" : "=v"(r) : "v"(lo), "v"(hi));
    return r;
}

__device__ __forceinline__ float max3f(float a, float b, float c) {
    float r;
    asm("v_max3_f32 %0, %1, %2, %3" : "=v"(r) : "v"(a), "v"(b), "v"(c));
    return r;
}

__device__ __forceinline__ u32 permb(u32 b, u32 a, u32 sel) {
    u32 r;
    asm("v_perm_b32 %0, %1, %2, %3" : "=v"(r) : "v"(b), "v"(a), "s"(sel));
    return r;
}

__device__ __forceinline__ f32x4 mfma32(s16x8 a, s16x8 b, f32x4 c) {
    return __builtin_amdgcn_mfma_f32_16x16x32_bf16(
        __builtin_bit_cast(bf16x8, a), __builtin_bit_cast(bf16x8, b), c, 0, 0, 0);
}

#define GLD16(gp, lp) __builtin_amdgcn_global_load_lds( \
    (__attribute__((address_space(1))) void*)(gp),      \
    (__attribute__((address_space(3))) void*)(lp), 16, 0, 0)

__global__ void k_mask_check(const int4* __restrict__ m4, int n4, int* flag) {
    bool z = false;
    for (int i = blockIdx.x * blockDim.x + threadIdx.x; i < n4;
         i += gridDim.x * blockDim.x) {
        int4 v = m4[i];
        if (v.x == 0 || v.y == 0 || v.z == 0 || v.w == 0) z = true;
    }
    if (__ballot(z)) {
        if ((threadIdx.x & 63) == 0) atomicAnd(flag, 0);
    }
}

// One fused fp32->bf16 convert pass over q,k,v,wq,wk,wv,wo. Also inits flag.
__global__ void k_cvt_all(const float4* __restrict__ q,  const float4* __restrict__ k,
                          const float4* __restrict__ v,  const float4* __restrict__ wq,
                          const float4* __restrict__ wk, const float4* __restrict__ wv,
                          const float4* __restrict__ wo,
                          uint64_t* xq, uint64_t* xk, uint64_t* xv,
                          uint64_t* bwq, uint64_t* bwk, uint64_t* bwv, uint64_t* bwo,
                          int* flag)
{
    if (blockIdx.x == 0 && threadIdx.x == 0) *flag = 1;
    const int NX = 2097152, NW = 262144;   // 2^21, 2^18 float4-chunks
    const int total = 3 * NX + 4 * NW;
    const int stride = gridDim.x * blockDim.x;
    for (int idx = blockIdx.x * blockDim.x + threadIdx.x; idx < total; idx += stride) {
        const float4* s; uint64_t* d; int off;
        if (idx < 3 * NX) {
            int ji = idx >> 21;
            off = idx & (NX - 1);
            s = ji == 0 ? q : ji == 1 ? k : v;
            d = ji == 0 ? xq : ji == 1 ? xk : xv;
        } else {
            int r = idx - 3 * NX;
            int ji = r >> 18;
            off = r & (NW - 1);
            s = ji == 0 ? wq : ji == 1 ? wk : ji == 2 ? wv : wo;
            d = ji == 0 ? bwq : ji == 1 ? bwk : ji == 2 ? bwv : bwo;
        }
        float4 f = s[off];
        union { u16 u[4]; uint64_t qq; } rr;
        rr.u[0] = f2bf(f.x); rr.u[1] = f2bf(f.y);
        rr.u[2] = f2bf(f.z); rr.u[3] = f2bf(f.w);
        d[off] = rr.qq;
    }
}

// C = A(MxK) * B(NxK)^T, swapped-operand MFMA: D[n][m], vectorized stores.
// XCD swizzle: each XCD owns 8 contiguous m-panels x all n (A+B L2-resident).
// MODE 0: fused QKV via blockIdx.z; bf16 store to head-split [B*H][L][64].
// MODE 1: fp32 store, plain row-major [M][N] (output projection).
template <int MODE>
__global__ __launch_bounds__(256) void k_gemm(
    const u16* __restrict__ A0, const u16* __restrict__ Bw0,
    u16* __restrict__ Cb0, float* __restrict__ Cf, float scale)
{
    constexpr int K = 1024;
    __shared__ char lA[128 * 32 * 2];
    __shared__ char lB[128 * 32 * 2];
    const int t = threadIdx.x, l = t & 63, w = t >> 6;
    const int q = l & 15, g = l >> 4;
    const int z = (MODE == 0) ? blockIdx.z : 0;
    const u16* A  = A0  + (size_t)z * 8388608;
    const u16* Bw = Bw0 + (size_t)z * 1048576;
    u16* Cb = (MODE == 0) ? Cb0 + (size_t)z * 8388608 : nullptr;
    const float scl = (MODE == 0 && z != 0) ? 1.0f : scale;
    const int lin = blockIdx.x;                       // 0..511
    const int ytile = ((lin & 7) << 3) | ((lin >> 3) & 7);
    const int xtile = lin >> 6;
    const int m0 = ytile * 128, n0 = xtile * 128;
    const int wr = (w >> 1) * 64, wc = (w & 1) * 64;

    f32x4 acc[4][4];
#pragma unroll
    for (int i = 0; i < 4; i++)
#pragma unroll
        for (int j = 0; j < 4; j++) acc[i][j] = (f32x4){0.f, 0.f, 0.f, 0.f};

    for (int k0 = 0; k0 < K; k0 += 32) {
#pragma unroll
        for (int c = 0; c < 2; c++) {
            int i = c * 256 + t;
            int row = i >> 2, sl = i & 3;
            int ss = sl ^ (row & 3);
            GLD16(A  + (size_t)(m0 + row) * K + k0 + ss * 8, lA + (i - l) * 16);
            GLD16(Bw + (size_t)(n0 + row) * K + k0 + ss * 8, lB + (i - l) * 16);
        }
        __syncthreads();
        s16x8 af[4], bfr[4];
#pragma unroll
        for (int mt = 0; mt < 4; mt++) {
            int r = wr + mt * 16 + q;
            af[mt] = *(const s16x8*)(lA + r * 64 + ((g ^ (r & 3)) * 16));
        }
#pragma unroll
        for (int nt = 0; nt < 4; nt++) {
            int r = wc + nt * 16 + q;
            bfr[nt] = *(const s16x8*)(lB + r * 64 + ((g ^ (r & 3)) * 16));
        }
#pragma unroll
        for (int mt = 0; mt < 4; mt++)
#pragma unroll
            for (int nt = 0; nt < 4; nt++)
                acc[mt][nt] = mfma32(bfr[nt], af[mt], acc[mt][nt]);
        __syncthreads();
    }

#pragma unroll
    for (int mt = 0; mt < 4; mt++) {
        int m = m0 + wr + mt * 16 + q;   // token (lane-contiguous)
#pragma unroll
        for (int nt = 0; nt < 4; nt++) {
            int n = n0 + wc + nt * 16 + g * 4;   // 4-consecutive n run
            f32x4 a = acc[mt][nt];
            if (MODE == 0) {
                int bb = m >> 11, row = m & 2047;
                int h = n >> 6, d = n & 63;
                s16x4 pk;
#pragma unroll
                for (int j = 0; j < 4; j++) pk[j] = (short)f2bf(a[j] * scl);
                *(s16x4*)(Cb + (((size_t)(bb * NH + h) * LQ + row) << 6) + d) = pk;
            } else {
                f32x4 o;
#pragma unroll
                for (int j = 0; j < 4; j++) o[j] = a[j] * scl;
                *(f32x4*)(Cf + (size_t)m * DM + n) = o;
            }
        }
    }
}

// Flash attention, swapped-QK^T in-register softmax, mfma32 PV (permuted-kc).
// r10 structure (512 blocks, 4 waves x 64 q-rows — traffic-optimal per r11's
// falsification of the occupancy thesis) + V-staging thread remap so the
// ds_write_b64 staging hits the 4-lane/slot floor: within a wave kg spans both
// bb2 parities and 4 kg&3 values (r10's map was wave-constant bb2 -> 8-way).
__global__ __launch_bounds__(256, 2) void k_attn(
    const u16* __restrict__ Qh, const u16* __restrict__ Kh,
    const u16* __restrict__ Vh, u16* __restrict__ ctx,
    const int* __restrict__ mask, const int* __restrict__ flag)
{
    __shared__ char lds[32768];
    char* lK0 = lds;           // lK[b] = lds + b*8192       [kc][d] 16B-xor-swz
    char* lV0 = lds + 16384;   // lV[b]: [d][kc-permuted], 16B-unit swz u^(d&7)
    const int t = threadIdx.x, l = t & 63, w = t >> 6;
    const int g = l >> 4, q = l & 15;
    const int p = blockIdx.x;
    const int bh = (p & 7) * 8 + ((p >> 3) >> 3);   // XCD-contiguous heads
    const int qt = ((p >> 3) & 7) * 256;
    const int allones = *flag;
    const size_t base = (size_t)bh * LQ * 64;
    // V-staging thread remap (bijective over 16x16): per-wave kg spans both
    // bb2 parities and 4 kg&3 values -> 16 write slots x 4 lanes = floor.
    const int dg = (l & 7) | ((w & 2) << 2);
    const int kg = (l >> 3) | ((w & 1) << 3);

    s16x8 qf[4][2];   // Q pre-scaled by log2(e)/8
#pragma unroll
    for (int qh = 0; qh < 4; qh++)
#pragma unroll
        for (int kh = 0; kh < 2; kh++)
            qf[qh][kh] = *(const s16x8*)(
                Qh + base + (size_t)(qt + w * 64 + qh * 16 + q) * 64 + kh * 32 + g * 8);

    f32x4 oacc[4][4];
#pragma unroll
    for (int qh = 0; qh < 4; qh++)
#pragma unroll
        for (int dt = 0; dt < 4; dt++) oacc[qh][dt] = (f32x4){0.f, 0.f, 0.f, 0.f};
    float mrow[4] = {-1e30f, -1e30f, -1e30f, -1e30f};
    float lrow[4] = {0.f, 0.f, 0.f, 0.f};

    auto stageK = [&](int kt, int b) {
#pragma unroll
        for (int c = 0; c < 2; c++) {
            int i = c * 256 + t;
            int row = i >> 3, sl = i & 7;
            GLD16(Kh + base + (size_t)(kt + row) * 64 + ((sl ^ (row & 7)) * 8),
                  lK0 + b * 8192 + (i - l) * 16);
        }
    };
    auto loadV = [&](int kt, s16x4* vr) {
#pragma unroll
        for (int j = 0; j < 4; j++)
            vr[j] = *(const s16x4*)(Vh + base + (size_t)(kt + kg * 4 + j) * 64 + dg * 4);
    };
    auto writeV = [&](const s16x4* vr, int b) {
        const u32 selLO = 0x05040100u, selHI = 0x07060302u;
        const int u = ((kg & 8) >> 1) | (kg & 3);
        const int bb2 = (kg >> 2) & 1;
        u32x2 vv[4];
#pragma unroll
        for (int j = 0; j < 4; j++) vv[j] = __builtin_bit_cast(u32x2, vr[j]);
#pragma unroll
        for (int jj = 0; jj < 4; jj++) {
            int d = dg * 4 + jj;
            u32 a0 = vv[0][jj >> 1], a1 = vv[1][jj >> 1];
            u32 a2 = vv[2][jj >> 1], a3 = vv[3][jj >> 1];
            u32 sel = (jj & 1) ? selHI : selLO;
            u32x2 pw = {permb(a1, a0, sel), permb(a3, a2, sel)};
            *(s16x4*)(lV0 + b * 8192 + d * 128 + ((u ^ (d & 7)) * 16) + bb2 * 8) =
                __builtin_bit_cast(s16x4, pw);
        }
    };

    { // prologue: tile 0 into buffer 0
        s16x4 vr[4];
        stageK(0, 0);
        loadV(0, vr);
        writeV(vr, 0);
    }

    int cur = 0;
    for (int kt = 0; kt < LQ; kt += 64) {
        __syncthreads();   // tile `cur` staged (vmcnt/lgkm drained), prev consumed
        const bool more = (kt + 64) < LQ;
        s16x4 vr[4];
        if (more) {        // issue next-tile staging early; latency hides under compute
            stageK(kt + 64, cur ^ 1);
            loadV(kt + 64, vr);
        }

        // --- S^T = K Q^T : lane holds row q=l&15, kc = ct*16 + g*4 + r
        f32x4 sc[4][4];
#pragma unroll
        for (int qh = 0; qh < 4; qh++)
#pragma unroll
            for (int ct = 0; ct < 4; ct++) sc[qh][ct] = (f32x4){0.f, 0.f, 0.f, 0.f};
        __builtin_amdgcn_s_setprio(1);
#pragma unroll
        for (int ct = 0; ct < 4; ct++) {
            int kc = ct * 16 + q;
#pragma unroll
            for (int kh = 0; kh < 2; kh++) {
                s16x8 kf = *(const s16x8*)(lK0 + cur * 8192 + kc * 128 +
                                           (((kh * 4 + g) ^ (kc & 7)) * 16));
#pragma unroll
                for (int qh = 0; qh < 4; qh++)
                    sc[qh][ct] = mfma32(kf, qf[qh][kh], sc[qh][ct]);
            }
        }
        __builtin_amdgcn_s_setprio(0);

        if (!allones) {   // slow correct path (unused for all-ones mask)
            int b = bh >> 4;
#pragma unroll
            for (int qh = 0; qh < 4; qh++)
#pragma unroll
                for (int ct = 0; ct < 4; ct++)
#pragma unroll
                    for (int r = 0; r < 4; r++) {
                        int qr = qt + w * 64 + qh * 16 + q;
                        int kc = kt + ct * 16 + g * 4 + r;
                        if (mask[(size_t)(b * LQ + qr) * LQ + kc] == 0)
                            sc[qh][ct][r] = -1e9f;
                    }
        }

        // --- online softmax (log2 domain); row max via v_max3 tree + 2 shfl
        float pm[4];
#pragma unroll
        for (int qh = 0; qh < 4; qh++) {
            float m0 = max3f(sc[qh][0][0], sc[qh][0][1], sc[qh][0][2]);
            m0 = max3f(m0, sc[qh][0][3], sc[qh][1][0]);
            m0 = max3f(m0, sc[qh][1][1], sc[qh][1][2]);
            m0 = max3f(m0, sc[qh][1][3], sc[qh][2][0]);
            m0 = max3f(m0, sc[qh][2][1], sc[qh][2][2]);
            m0 = max3f(m0, sc[qh][2][3], sc[qh][3][0]);
            m0 = max3f(m0, sc[qh][3][1], sc[qh][3][2]);
            m0 = fmaxf(m0, sc[qh][3][3]);
            m0 = fmaxf(m0, __shfl_xor(m0, 16, 64));
            m0 = fmaxf(m0, __shfl_xor(m0, 32, 64));
            pm[qh] = m0;
        }
        bool ok = pm[0] <= mrow[0] + 8.f;
        ok = ok && (pm[1] <= mrow[1] + 8.f);
        ok = ok && (pm[2] <= mrow[2] + 8.f);
        ok = ok && (pm[3] <= mrow[3] + 8.f);
        if (!__all(ok)) {
#pragma unroll
            for (int qh = 0; qh < 4; qh++) {
                float nm = fmaxf(mrow[qh], pm[qh]);
                float corr = fexp2(mrow[qh] - nm);
                mrow[qh] = nm;
                lrow[qh] *= corr;
                float cv[4];
#pragma unroll
                for (int r = 0; r < 4; r++) cv[r] = __shfl(corr, g * 4 + r, 64);
#pragma unroll
                for (int dt = 0; dt < 4; dt++)
#pragma unroll
                    for (int r = 0; r < 4; r++) oacc[qh][dt][r] *= cv[r];
            }
        }
        // exp + rowsum + pack A-fragments for mfma32 PV (permuted-kc, lane-local)
        s16x8 pa32[4][2];
#pragma unroll
        for (int qh = 0; qh < 4; qh++) {
            float rs = 0.f;
#pragma unroll
            for (int ct = 0; ct < 4; ct++)
#pragma unroll
                for (int r = 0; r < 4; r++) {
                    float e = fexp2(sc[qh][ct][r] - mrow[qh]);
                    sc[qh][ct][r] = e;
                    rs += e;
                }
            rs += __shfl_xor(rs, 16, 64);
            rs += __shfl_xor(rs, 32, 64);
            lrow[qh] += rs;
#pragma unroll
            for (int s = 0; s < 2; s++) {
                u32x4 pv;
                pv.x = cvtpk(sc[qh][2 * s][0],     sc[qh][2 * s][1]);
                pv.y = cvtpk(sc[qh][2 * s][2],     sc[qh][2 * s][3]);
                pv.z = cvtpk(sc[qh][2 * s + 1][0], sc[qh][2 * s + 1][1]);
                pv.w = cvtpk(sc[qh][2 * s + 1][2], sc[qh][2 * s + 1][3]);
                pa32[qh][s] = __builtin_bit_cast(s16x8, pv);
            }
        }

        // --- O += P V  (mfma32, B-fragment = one ds_read_b128 per (dt,s))
        __builtin_amdgcn_s_setprio(1);
#pragma unroll
        for (int dt = 0; dt < 4; dt++) {
#pragma unroll
            for (int s = 0; s < 2; s++) {
                s16x8 vf = *(const s16x8*)(lV0 + cur * 8192 + (dt * 16 + q) * 128 +
                                           (((4 * s + g) ^ (q & 7)) * 16));
#pragma unroll
                for (int qh = 0; qh < 4; qh++)
                    oacc[qh][dt] = mfma32(pa32[qh][s], vf, oacc[qh][dt]);
            }
        }
        __builtin_amdgcn_s_setprio(0);

        if (more) writeV(vr, cur ^ 1);   // vmcnt wait lands here, after compute
        cur ^= 1;
    }

    // --- epilogue: normalize -> per-wave LDS region (swizzled) -> 128B/lane stores
    __syncthreads();                  // all waves done reading lK/lV
    char* eb = lds + w * 8192;        // 64 rows x 128B per wave
#pragma unroll
    for (int qh = 0; qh < 4; qh++) {
        float lv[4];
#pragma unroll
        for (int r = 0; r < 4; r++) lv[r] = 1.f / __shfl(lrow[qh], g * 4 + r, 64);
#pragma unroll
        for (int dt = 0; dt < 4; dt++)
#pragma unroll
            for (int r = 0; r < 4; r++) {
                int row = qh * 16 + g * 4 + r;
                int cb = ((dt * 16 + q) * 2) ^ ((row & 7) << 4);
                *(u16*)(eb + row * 128 + cb) = f2bf(oacc[qh][dt][r] * lv[r]);
            }
    }
    __syncthreads();
    const int b = bh >> 4, h = bh & 15;
    const int token = qt + w * 64 + l;
    u16* gp = ctx + (size_t)(b * LQ + token) * DM + h * 64;
#pragma unroll
    for (int j = 0; j < 8; j++) {
        int cb = (j * 16) ^ ((l & 7) << 4);
        *(s16x8*)(gp + j * 8) = *(const s16x8*)(eb + l * 128 + cb);
    }
}

extern "C" void kernel_launch(void* const* d_in, const int* in_sizes, int n_in,
                              void* d_out, int out_size, void* d_ws, size_t ws_size,
                              hipStream_t stream)
{
    const float* q  = (const float*)d_in[0];
    const float* k  = (const float*)d_in[1];
    const float* v  = (const float*)d_in[2];
    const float* wq = (const float*)d_in[3];
    const float* wk = (const float*)d_in[4];
    const float* wv = (const float*)d_in[5];
    const float* wo = (const float*)d_in[6];
    const int* mask = (const int*)d_in[7];

    char* ws = (char*)d_ws;
    const size_t SX = (size_t)8192 * 1024 * 2;
    const size_t SW = (size_t)1024 * 1024 * 2;
    u16* xq  = (u16*)(ws);                     // xq,xk,xv contiguous (8M u16 each)
    u16* xk  = (u16*)(ws + SX);
    u16* xv  = (u16*)(ws + 2 * SX);
    u16* bwq = (u16*)(ws + 3 * SX);            // bwq,bwk,bwv contiguous (1M u16 each)
    u16* bwk = (u16*)(ws + 3 * SX + SW);
    u16* bwv = (u16*)(ws + 3 * SX + 2 * SW);
    u16* bwo = (u16*)(ws + 3 * SX + 3 * SW);
    u16* Qh  = (u16*)(ws + 3 * SX + 4 * SW);   // Qh,Kh,Vh contiguous (8M u16 each)
    u16* Kh  = (u16*)(ws + 4 * SX + 4 * SW);
    u16* Vh  = (u16*)(ws + 5 * SX + 4 * SW);
    u16* ctx = (u16*)(ws + 6 * SX + 4 * SW);
    int* flag = (int*)(ws + 7 * SX + 4 * SW);

    k_cvt_all<<<2048, 256, 0, stream>>>(
        (const float4*)q, (const float4*)k, (const float4*)v,
        (const float4*)wq, (const float4*)wk, (const float4*)wv, (const float4*)wo,
        (uint64_t*)xq, (uint64_t*)xk, (uint64_t*)xv,
        (uint64_t*)bwq, (uint64_t*)bwk, (uint64_t*)bwv, (uint64_t*)bwo, flag);
    k_mask_check<<<2048, 256, 0, stream>>>((const int4*)mask,
                                           (4 * 2048 * 2048) / 4, flag);

    // Fused QKV projection (z selects q/k/v); Q scaled by log2(e)/8 (exp2 softmax)
    k_gemm<0><<<dim3(512, 1, 3), 256, 0, stream>>>(xq, bwq, Qh, nullptr,
                                                   0.18033688011112042f);

    k_attn<<<512, 256, 0, stream>>>(Qh, Kh, Vh, ctx, mask, flag);

    k_gemm<1><<<dim3(512), 256, 0, stream>>>(ctx, bwo, nullptr, (float*)d_out, 1.0f);
}